// Round 7
// baseline (105.472 us; speedup 1.0000x reference)
//
#include <hip/hip_runtime.h>

#define NROWS 4096
#define VCOLS 30522
#define PAD   512
#define NF4   7630      // aligned float4 chunks per row after head/tail peel
#define BLOCK 256
#define WPB   4         // waves per block = segments per row
#define QCH   1908      // float4 chunks per segment (4*1908 = 7632 >= 7630)
#define NITW  32        // padded iters per wave (32*64 = 2048 >= 1908), /4 = 8 groups
#define DEPTH 4         // outstanding 1KB wave-loads per wave

typedef float fx4 __attribute__((ext_vector_type(4)));
typedef float fx2 __attribute__((ext_vector_type(2)));

__device__ __forceinline__ int lanes_below(unsigned long long m) {
    int c = __builtin_amdgcn_mbcnt_lo((unsigned)m, 0u);
    return __builtin_amdgcn_mbcnt_hi((unsigned)(m >> 32), c);
}

__device__ __forceinline__ fx4 nt_load4(const float* p) {
    return __builtin_nontemporal_load(reinterpret_cast<const fx4*>(p));
}

__global__ __launch_bounds__(BLOCK, 8) void sparse_compact_block(
    const float* __restrict__ in, float* __restrict__ out)
{
    __shared__ float2 sbuf[WPB][PAD];   // per-wave segment staging {col,val}, 16KB
    __shared__ int scnt[WPB];

    const int tid  = threadIdx.x;
    const int lane = tid & 63;
    const int wid  = tid >> 6;
    const int row  = blockIdx.x;

    float* orow = out + (size_t)row * (2 * PAD);
    const float* rbase = in + (size_t)row * VCOLS;
    const int odd = row & 1;
    const int coff = odd ? 2 : 0;
    const float* irow4 = rbase + coff;   // 16B-aligned; chunk i at +4*i

    int base = 0;

    // Head peel (odd rows start 8 mod 16): cols 0,1 belong to wave 0's segment.
    if (odd && wid == 0) {
        float2 h = *reinterpret_cast<const float2*>(rbase);
        int n0 = (h.x != 0.0f), n1 = (h.y != 0.0f);
        if (lane == 0) {
            if (n0) sbuf[0][0]  = make_float2(0.0f, h.x);
            if (n1) sbuf[0][n0] = make_float2(1.0f, h.y);
        }
        base = n0 + n1;
    }

    const int segStart = wid * QCH;
    const int segEnd   = (segStart + QCH < NF4) ? segStart + QCH : NF4;

    // 4-deep pipeline prologue (first 256 chunks of every segment in range).
    int idx = segStart + lane;
    fx4 c0 = nt_load4(irow4 + 4 * idx);
    fx4 c1 = nt_load4(irow4 + 4 * (idx + 64));
    fx4 c2 = nt_load4(irow4 + 4 * (idx + 128));
    fx4 c3 = nt_load4(irow4 + 4 * (idx + 192));

#define STEP(CREG)                                                            \
    do {                                                                      \
        int pidx = idx + DEPTH * 64;                                          \
        if (pidx >= NF4) pidx = NF4 - 1;   /* clamp: keeps vmcnt static */    \
        fx4 nv = nt_load4(irow4 + 4 * pidx);                                  \
        const bool pv = (idx < segEnd);                                       \
        const bool p0 = pv && (CREG.x != 0.0f);                               \
        const bool p1 = pv && (CREG.y != 0.0f);                               \
        const bool p2 = pv && (CREG.z != 0.0f);                               \
        const bool p3 = pv && (CREG.w != 0.0f);                               \
        const unsigned long long b0 = __ballot(p0);                           \
        const unsigned long long b1 = __ballot(p1);                           \
        const unsigned long long b2 = __ballot(p2);                           \
        const unsigned long long b3 = __ballot(p3);                           \
        int d = base + lanes_below(b0) + lanes_below(b1)                      \
                     + lanes_below(b2) + lanes_below(b3);                     \
        const int tot = __popcll(b0) + __popcll(b1)                           \
                      + __popcll(b2) + __popcll(b3);                          \
        const float cf = (float)(coff + 4 * idx);                             \
        if (p0 && d < PAD) sbuf[wid][d] = make_float2(cf,        CREG.x); d += p0; \
        if (p1 && d < PAD) sbuf[wid][d] = make_float2(cf + 1.0f, CREG.y); d += p1; \
        if (p2 && d < PAD) sbuf[wid][d] = make_float2(cf + 2.0f, CREG.z); d += p2; \
        if (p3 && d < PAD) sbuf[wid][d] = make_float2(cf + 3.0f, CREG.w);          \
        base += tot;                                                          \
        CREG = nv;                                                            \
        idx += 64;                                                            \
    } while (0)

    for (int g = 0; g < NITW / DEPTH; ++g) {
        STEP(c0); STEP(c1); STEP(c2); STEP(c3);
        if (base >= PAD) break;   // wave-uniform; segment buffer full (capped)
    }
#undef STEP

    // Tail peel (even rows): cols 30520, 30521 belong to wave 3's segment.
    if (!odd && wid == (WPB - 1) && base < PAD) {
        float2 t = *reinterpret_cast<const float2*>(rbase + 30520);
        int n0 = (t.x != 0.0f), n1 = (t.y != 0.0f);
        if (lane == 0) {
            if (n0) sbuf[wid][base] = make_float2(30520.0f, t.x);
            const int dd = base + n0;
            if (n1 && dd < PAD) sbuf[wid][dd] = make_float2(30521.0f, t.y);
        }
        base += n0 + n1;
    }

    if (lane == 0) scnt[wid] = (base < PAD) ? base : PAD;  // capped count
    __syncthreads();

    // Merge: prefix over capped segment counts, then gather + coalesced write.
    const int n0 = scnt[0], n1 = scnt[1], n2 = scnt[2], n3 = scnt[3];
    const int cum1 = n0;
    const int cum2 = cum1 + n1;
    const int cum3 = cum2 + n2;
    int total = cum3 + n3;
    if (total > PAD) total = PAD;

    // 512 slots, 2 consecutive per thread -> float2 stores for cols and vals.
    const int i0 = 2 * tid;
    fx2 cols, vals;
    #pragma unroll
    for (int k = 0; k < 2; ++k) {
        const int i = i0 + k;
        float c = 0.0f, v = 0.0f;
        if (i < total) {
            const int s = (i >= cum1) + (i >= cum2) + (i >= cum3);
            const int off = i - (s == 0 ? 0 : (s == 1 ? cum1 : (s == 2 ? cum2 : cum3)));
            const float2 e = sbuf[s][off];
            c = e.x; v = e.y;
        }
        if (k == 0) { cols.x = c; vals.x = v; } else { cols.y = c; vals.y = v; }
    }
    __builtin_nontemporal_store(cols, reinterpret_cast<fx2*>(&orow[i0]));
    __builtin_nontemporal_store(vals, reinterpret_cast<fx2*>(&orow[PAD + i0]));
}

extern "C" void kernel_launch(void* const* d_in, const int* in_sizes, int n_in,
                              void* d_out, int out_size, void* d_ws, size_t ws_size,
                              hipStream_t stream)
{
    const float* in = (const float*)d_in[0];
    float* out = (float*)d_out;
    sparse_compact_block<<<NROWS, BLOCK, 0, stream>>>(in, out);
}

// Round 8
// 100.332 us; speedup vs baseline: 1.0512x; 1.0512x over previous
//
#include <hip/hip_runtime.h>

#define NROWS 4096
#define VCOLS 30522
#define PAD   512
#define NF4   7630      // aligned float4 chunks per row after head/tail peel
#define BLOCK 256
#define WPB   4         // waves per block = segments per row
#define QCH   1908      // float4 chunks per segment (4*1908 = 7632 >= 7630)
#define DEPTH 4         // outstanding 1KB wave-loads per wave
#define SSTRIDE (PAD + 64)   // 512 data slots + 64 per-lane dump slots

__device__ __forceinline__ int lanes_below(unsigned long long m) {
    int c = __builtin_amdgcn_mbcnt_lo((unsigned)m, 0u);
    return __builtin_amdgcn_mbcnt_hi((unsigned)(m >> 32), c);
}

__global__ __launch_bounds__(BLOCK, 8) void sparse_compact_block(
    const float* __restrict__ in, float* __restrict__ out)
{
    __shared__ float2 sbuf[WPB][SSTRIDE];   // {col,val} staging + dump, 18.4KB
    __shared__ int scnt[WPB];

    const int tid  = threadIdx.x;
    const int lane = tid & 63;
    const int wid  = tid >> 6;
    const int row  = blockIdx.x;

    float* orow = out + (size_t)row * (2 * PAD);
    const float* rbase = in + (size_t)row * VCOLS;
    const int odd = row & 1;
    const int coff = odd ? 2 : 0;
    const float4* irow4 = reinterpret_cast<const float4*>(rbase + coff);

    int base = 0;

    // Head peel (odd rows start 8 mod 16): cols 0,1 belong to wave 0's segment.
    if (odd && wid == 0) {
        float2 h = *reinterpret_cast<const float2*>(rbase);
        int n0 = (h.x != 0.0f), n1 = (h.y != 0.0f);
        if (lane == 0) {
            if (n0) sbuf[0][0]  = make_float2(0.0f, h.x);
            if (n1) sbuf[0][n0] = make_float2(1.0f, h.y);
        }
        base = n0 + n1;
    }

    const int segStart = wid * QCH;
    const int segEnd   = (segStart + QCH < NF4) ? segStart + QCH : NF4;
    const int dump     = PAD + lane;            // private junk slot per lane

    // Column (as float) of this lane's first element, advanced +256 per STEP.
    float cfl = (float)(coff + 4 * (segStart + lane));

    // 4-deep pipeline prologue (first 256 chunks of every segment in range).
    int idx = segStart + lane;
    float4 c0 = irow4[idx];
    float4 c1 = irow4[idx + 64];
    float4 c2 = irow4[idx + 128];
    float4 c3 = irow4[idx + 192];

    // Branchless consume: every component does exactly one ds_write_b64;
    // inactive/overflow lanes are routed to junk slots via cndmask.
#define SCATTER(CREG)                                                         \
    do {                                                                      \
        const bool p0 = (CREG.x != 0.0f);                                     \
        const bool p1 = (CREG.y != 0.0f);                                     \
        const bool p2 = (CREG.z != 0.0f);                                     \
        const bool p3 = (CREG.w != 0.0f);                                     \
        const unsigned long long b0 = __ballot(p0);                           \
        const unsigned long long b1 = __ballot(p1);                           \
        const unsigned long long b2 = __ballot(p2);                           \
        const unsigned long long b3 = __ballot(p3);                           \
        int d = base + lanes_below(b0) + lanes_below(b1)                      \
                     + lanes_below(b2) + lanes_below(b3);                     \
        int s;                                                                \
        s = p0 ? (d < PAD ? d : PAD) : dump;                                  \
        sbuf[wid][s] = make_float2(cfl,        CREG.x); d += p0;              \
        s = p1 ? (d < PAD ? d : PAD) : dump;                                  \
        sbuf[wid][s] = make_float2(cfl + 1.0f, CREG.y); d += p1;              \
        s = p2 ? (d < PAD ? d : PAD) : dump;                                  \
        sbuf[wid][s] = make_float2(cfl + 2.0f, CREG.z); d += p2;              \
        s = p3 ? (d < PAD ? d : PAD) : dump;                                  \
        sbuf[wid][s] = make_float2(cfl + 3.0f, CREG.w);                       \
        base += __popcll(b0) + __popcll(b1) + __popcll(b2) + __popcll(b3);    \
        cfl += 256.0f;                                                        \
        idx += 64;                                                            \
    } while (0)

    // Clean STEP: no consume mask, no prefetch clamp (statically in-bounds
    // for iters 0..23: idx+DEPTH*64 <= segStart+1791+256 < NF4 for all waves).
#define STEP_CLEAN(CREG)                                                      \
    do { float4 nv = irow4[idx + DEPTH * 64]; SCATTER(CREG); CREG = nv; } while (0)

    // Tail STEP A (iters 24..27): clamped prefetch, consume still in-bounds.
#define STEP_A(CREG)                                                          \
    do {                                                                      \
        int pidx = idx + DEPTH * 64;                                          \
        if (pidx >= NF4) pidx = NF4 - 1;                                      \
        float4 nv = irow4[pidx];                                              \
        SCATTER(CREG); CREG = nv;                                             \
    } while (0)

    // Tail STEP B (iters 28..31): no prefetch; mask out-of-segment lanes.
#define STEP_B(CREG)                                                          \
    do {                                                                      \
        if (idx >= segEnd) { CREG.x = 0.0f; CREG.y = 0.0f; CREG.z = 0.0f; CREG.w = 0.0f; } \
        SCATTER(CREG);                                                        \
    } while (0)

    for (int g = 0; g < 6; ++g) {           // 24 clean iterations
        STEP_CLEAN(c0); STEP_CLEAN(c1); STEP_CLEAN(c2); STEP_CLEAN(c3);
        if (base >= PAD) break;             // wave-uniform; segment cap reached
    }
    if (base < PAD) {
        STEP_A(c0); STEP_A(c1); STEP_A(c2); STEP_A(c3);
        STEP_B(c0); STEP_B(c1); STEP_B(c2); STEP_B(c3);
    }
#undef STEP_CLEAN
#undef STEP_A
#undef STEP_B
#undef SCATTER

    // Tail peel (even rows): cols 30520, 30521 belong to wave 3's segment.
    if (!odd && wid == (WPB - 1) && base < PAD) {
        float2 t = *reinterpret_cast<const float2*>(rbase + 30520);
        int n0 = (t.x != 0.0f), n1 = (t.y != 0.0f);
        if (lane == 0) {
            if (n0) sbuf[wid][base] = make_float2(30520.0f, t.x);
            const int dd = base + n0;
            if (n1 && dd < PAD) sbuf[wid][dd] = make_float2(30521.0f, t.y);
        }
        base += n0 + n1;
    }

    if (lane == 0) scnt[wid] = (base < PAD) ? base : PAD;  // capped count
    __syncthreads();

    // Merge: prefix over capped segment counts, then gather + coalesced write.
    const int n0 = scnt[0], n1 = scnt[1], n2 = scnt[2], n3 = scnt[3];
    const int cum1 = n0;
    const int cum2 = cum1 + n1;
    const int cum3 = cum2 + n2;
    int total = cum3 + n3;
    if (total > PAD) total = PAD;

    // 512 slots, 2 consecutive per thread -> float2 stores for cols and vals.
    const int i0 = 2 * tid;
    float2 cols, vals;
    #pragma unroll
    for (int k = 0; k < 2; ++k) {
        const int i = i0 + k;
        float c = 0.0f, v = 0.0f;
        if (i < total) {
            const int s = (i >= cum1) + (i >= cum2) + (i >= cum3);
            const int off = i - (s == 0 ? 0 : (s == 1 ? cum1 : (s == 2 ? cum2 : cum3)));
            const float2 e = sbuf[s][off];
            c = e.x; v = e.y;
        }
        if (k == 0) { cols.x = c; vals.x = v; } else { cols.y = c; vals.y = v; }
    }
    *reinterpret_cast<float2*>(&orow[i0])       = cols;
    *reinterpret_cast<float2*>(&orow[PAD + i0]) = vals;
}

extern "C" void kernel_launch(void* const* d_in, const int* in_sizes, int n_in,
                              void* d_out, int out_size, void* d_ws, size_t ws_size,
                              hipStream_t stream)
{
    const float* in = (const float*)d_in[0];
    float* out = (float*)d_out;
    sparse_compact_block<<<NROWS, BLOCK, 0, stream>>>(in, out);
}